// Round 16
// baseline (167.810 us; speedup 1.0000x reference)
//
#include <hip/hip_runtime.h>
#include <hip/hip_bf16.h>
#include <math.h>

#define HW 128
#define NPIX 16384           // 128*128
#define KTOP 128
#define PPAIR 8128           // 128*127/2
#define NB 2
#define DIMLOI 128
#define NROWS (NB*PPAIR)     // 16256
#define MPAD 16384           // NROWS padded to full tiles (pad rows clamp-duplicated)

typedef __bf16 bf16x8 __attribute__((ext_vector_type(8)));
typedef float floatx4 __attribute__((ext_vector_type(4)));
typedef float floatx8 __attribute__((ext_vector_type(8)));

// key = (float_bits(v) << 32) | (0xFFFFFFFF - idx): unique; descending key order
// == lax.top_k order (desc value, asc index on ties); v >= 0 so bit order == float order.
__device__ __forceinline__ unsigned long long mk_key(float v, int idx) {
    return ((unsigned long long)__float_as_uint(v) << 32) |
           (unsigned long long)(0xFFFFFFFFu - (unsigned)idx);
}

__device__ __forceinline__ unsigned long long shfl_xor_u64(unsigned long long x, int m) {
    unsigned lo = (unsigned)x, hi = (unsigned)(x >> 32);
    lo = __shfl_xor(lo, m);
    hi = __shfl_xor(hi, m);
    return ((unsigned long long)hi << 32) | lo;
}

// one bitonic exchange stage over 256 elements held as V[4], element index i = q*64 + lane.
// MUST be called with compile-time-constant j,k (rule #20: runtime V[p] index -> scratch).
__device__ __forceinline__ void bitonic_stage(unsigned long long V[4], int lane, int j, int k) {
    if (j >= 64) {
        int qm = j >> 6;    // 1 or 2
        #pragma unroll
        for (int q = 0; q < 4; q++) {
            int p = q ^ qm;
            if (p > q) {
                int i = q * 64 + lane;
                bool desc = ((i & k) == 0);
                unsigned long long a = V[q], b = V[p];
                unsigned long long hi = a > b ? a : b, lo = a > b ? b : a;
                V[q] = desc ? hi : lo;
                V[p] = desc ? lo : hi;
            }
        }
    } else {
        #pragma unroll
        for (int q = 0; q < 4; q++) {
            int i = q * 64 + lane;
            unsigned long long p = shfl_xor_u64(V[q], j);
            bool lower = (lane & j) == 0;
            bool desc = ((i & k) == 0);
            bool keepmax = (desc == lower);
            unsigned long long mx = V[q] > p ? V[q] : p;
            unsigned long long mn = V[q] > p ? p : V[q];
            V[q] = keepmax ? mx : mn;
        }
    }
}

__device__ __forceinline__ void sort256_desc(unsigned long long V[4], int lane) {
    #pragma unroll
    for (int k = 2; k <= 256; k <<= 1)
        #pragma unroll
        for (int j = k >> 1; j >= 1; j >>= 1)
            bitonic_stage(V, lane, j, k);
}

__device__ __forceinline__ void merge256_desc(unsigned long long V[4], int lane) {
    #pragma unroll
    for (int j = 128; j >= 1; j >>= 1)
        bitonic_stage(V, lane, j, 256);
}

// ---------------- stage 1: per-8-row-strip softmax + NMS + exact top-128 ----------------
__global__ __launch_bounds__(256) void nms_sort_kernel(const float* __restrict__ inp,
                                                       unsigned long long* __restrict__ tkeys) {
    __shared__ float jm[10 * HW];
    __shared__ unsigned long long cand[256];
    __shared__ int scnt;
    int blk = blockIdx.x;        // 0..15
    int b   = blockIdx.y;
    int tid = threadIdx.x, lane = tid & 63;
    int r0  = blk * 8;
    int rlo = (r0 > 0) ? r0 - 1 : 0;
    int rhi = (r0 + 8 < HW) ? r0 + 8 : HW - 1;
    int nrows = rhi - rlo + 1;

    for (int i = tid; i < nrows * HW; i += 256) {
        int pix = rlo * HW + i;
        float l0 = inp[((long)b * 5 + 0) * NPIX + pix];
        float l1 = inp[((long)b * 5 + 1) * NPIX + pix];
        float m = fmaxf(l0, l1);
        float e0 = expf(l0 - m), e1 = expf(l1 - m);
        jm[i] = e1 / (e0 + e1);
    }
    cand[tid] = 0ull;
    if (tid == 0) scnt = 0;
    __syncthreads();

    #pragma unroll
    for (int i = 0; i < 4; i++) {
        int pl = i * 256 + tid;
        int r = r0 + (pl >> 7), c = pl & 127;
        float v = jm[(r - rlo) * HW + c];
        float m = v;
        for (int dr = -1; dr <= 1; dr++) {
            int rr = r + dr;
            if (rr < 0 || rr >= HW) continue;
            for (int dc = -1; dc <= 1; dc++) {
                int cc = c + dc;
                if (cc < 0 || cc >= HW) continue;
                m = fmaxf(m, jm[(rr - rlo) * HW + cc]);
            }
        }
        float nv = (v == m) ? v : 0.f;
        bool has = (nv > 0.f);
        unsigned long long mask = __ballot(has);
        int n = __popcll(mask);
        int wbase = 0;
        if (lane == 0 && n) wbase = atomicAdd(&scnt, n);
        wbase = __shfl(wbase, 0);
        if (has) {
            int pos = wbase + __popcll(mask & ((1ull << lane) - 1ull));
            if (pos < 256) cand[pos] = mk_key(nv, r * HW + c);
        }
    }
    __syncthreads();
    if (blk == 0 && tid < 128 && tid >= scnt) cand[tid] = mk_key(0.f, tid);
    __syncthreads();

    if (tid < 64) {
        unsigned long long V[4];
        #pragma unroll
        for (int q = 0; q < 4; q++) V[q] = cand[q * 64 + lane];
        sort256_desc(V, lane);
        #pragma unroll
        for (int q = 0; q < 2; q++)
            tkeys[((long)b * 16 + blk) * 128 + q * 64 + lane] = V[q];
    }
}

// ---------------- stage 2: merge 16 sorted lists -> global top-128, emit xy ----------------
__global__ __launch_bounds__(512) void topk_merge_kernel(const unsigned long long* __restrict__ tkeys,
                                                         const float* __restrict__ inp,
                                                         float* __restrict__ xy) {
    __shared__ unsigned long long Lb[16 * 128];
    __shared__ unsigned long long Mb[8 * 128];
    int b = blockIdx.x;
    int tid = threadIdx.x, w = tid >> 6, lane = tid & 63;
    for (int i = tid; i < 16 * 128; i += 512) Lb[i] = tkeys[(long)b * 2048 + i];
    __syncthreads();

    unsigned long long* src = Lb;
    unsigned long long* dst = Mb;
    for (int nact = 8; nact >= 1; nact >>= 1) {
        unsigned long long V[4];
        if (w < nact) {
            #pragma unroll
            for (int q = 0; q < 2; q++) V[q] = src[(2 * w) * 128 + q * 64 + lane];
            #pragma unroll
            for (int q = 2; q < 4; q++) {
                int t = (q - 2) * 64 + lane;
                V[q] = src[(2 * w + 1) * 128 + 127 - t];
            }
            merge256_desc(V, lane);
        }
        __syncthreads();
        if (w < nact) {
            #pragma unroll
            for (int q = 0; q < 2; q++) dst[w * 128 + q * 64 + lane] = V[q];
        }
        __syncthreads();
        unsigned long long* tmp = src; src = dst; dst = tmp;
    }

    if (tid < KTOP) {
        unsigned long long key = src[tid];
        int wi = (int)(0xFFFFFFFFu - (unsigned)(key & 0xFFFFFFFFull));
        int row = wi >> 7, col = wi & 127;
        float l3 = inp[((long)b * 5 + 3) * NPIX + wi];
        float l4 = inp[((long)b * 5 + 4) * NPIX + wi];
        float joy = 1.f / (1.f + expf(-l3)) - 0.5f;
        float jox = 1.f / (1.f + expf(-l4)) - 0.5f;
        xy[(b * KTOP + tid) * 2 + 0] = (float)row + joy + 0.5f;
        xy[(b * KTOP + tid) * 2 + 1] = (float)col + jox + 0.5f;
    }
}

// pair index p -> (u,v) of triu_indices(128, k=1)
__device__ __forceinline__ void pair_uv(int p, int& u, int& v) {
    int uu = (int)((255.0 - sqrt(65025.0 - 8.0 * (double)p)) * 0.5);
    if (uu < 0) uu = 0;
    while (uu * (255 - uu) / 2 > p) uu--;
    while ((uu + 1) * (255 - (uu + 1)) / 2 <= p) uu++;
    u = uu;
    v = uu + 1 + (p - uu * (255 - uu) / 2);
}

// ---------------- fused weight prep: w1^T, w2^T (bf16) and fc1_w convert ----------------
__global__ void prep_weights(const float* __restrict__ w1, const float* __restrict__ w2,
                             const float* __restrict__ fc1w,
                             __hip_bfloat16* __restrict__ w1t, __hip_bfloat16* __restrict__ w2t,
                             __hip_bfloat16* __restrict__ fc1wb) {
    int z = blockIdx.z;
    int tx = threadIdx.x & 31, ty = threadIdx.x >> 5;
    if (z < 2) {
        const float* W = z ? w2 : w1;
        __hip_bfloat16* Wt = z ? w2t : w1t;
        __shared__ float t[32][33];
        int k0 = blockIdx.x * 32, n0 = blockIdx.y * 32;
        #pragma unroll
        for (int i = 0; i < 32; i += 8)
            t[ty + i][tx] = W[(long)(k0 + ty + i) * 1024 + n0 + tx];
        __syncthreads();
        #pragma unroll
        for (int i = 0; i < 32; i += 8)
            Wt[(long)(n0 + ty + i) * 1024 + k0 + tx] = __float2bfloat16(t[tx][ty + i]);
    } else {
        if (blockIdx.x < 4 && blockIdx.y < 8) {
            int r0 = blockIdx.x * 32, c0 = blockIdx.y * 32;
            #pragma unroll
            for (int i = 0; i < 32; i += 8) {
                long idx = (long)(r0 + ty + i) * 256 + c0 + tx;
                fc1wb[idx] = __float2bfloat16(fc1w[idx]);
            }
        }
    }
}

__device__ __forceinline__ void gload_lds16(const void* g, void* l) {
    __builtin_amdgcn_global_load_lds(
        (const __attribute__((address_space(1))) void*)g,
        (__attribute__((address_space(3))) void*)l, 16, 0, 0);
}

// ---------------- fused transpose + xf GEMM ----------------
#define SA 264   // A_lds row stride in __bf16 (128 rows x 264; pad breaks 512B stride)

__global__ __launch_bounds__(256) void xf_fused_kernel(
    const float* __restrict__ features, const __hip_bfloat16* __restrict__ fc1wb,
    const float* __restrict__ bias, __hip_bfloat16* __restrict__ C0) {
    __shared__ __align__(16) __bf16 A_lds[128 * SA];              // 67.6 KB
    __shared__ __align__(16) unsigned short B_lds[128 * 32 * 8];  // 64 KB
    int tid = threadIdx.x;
    int lane = tid & 63, wid = tid >> 6;
    int wr = wid >> 1, wc = wid & 1;
    int b = blockIdx.z;
    long pix0 = (long)blockIdx.x * 128;

    #pragma unroll
    for (int it = 0; it < 16; it++) {
        int slot = it * 256 + tid;
        int r = slot >> 5, s = slot & 31;
        int ss = s ^ (r & 7);
        gload_lds16(fc1wb + (size_t)r * 256 + ss * 8,
                    (char*)B_lds + (size_t)(it * 4096 + wid * 1024));
    }
    {
        int c = tid;
        const float* src = features + ((long)b * 256 + c) * NPIX + pix0;
        #pragma unroll
        for (int p4 = 0; p4 < 32; p4++) {
            floatx4 v = *(const floatx4*)(src + p4 * 4);
            #pragma unroll
            for (int e = 0; e < 4; e++)
                A_lds[(p4 * 4 + e) * SA + c] = (__bf16)v[e];
        }
    }
    __syncthreads();

    floatx4 acc[4][4];
    #pragma unroll
    for (int i = 0; i < 4; i++)
        #pragma unroll
        for (int j = 0; j < 4; j++) acc[i][j] = (floatx4){0.f, 0.f, 0.f, 0.f};

    int r15 = lane & 15;
    #pragma unroll
    for (int ks = 0; ks < 8; ks++) {
        int s = (lane >> 4) + ks * 4;
        bf16x8 af[4], bfr[4];
        #pragma unroll
        for (int mi = 0; mi < 4; mi++) {
            int R = wr * 64 + mi * 16 + r15;
            af[mi] = *(const bf16x8*)&A_lds[R * SA + s * 8];
        }
        #pragma unroll
        for (int ni = 0; ni < 4; ni++) {
            int Rn = wc * 64 + ni * 16 + r15;
            bfr[ni] = *(const bf16x8*)&B_lds[(size_t)Rn * 256 + ((s ^ (Rn & 7)) << 3)];
        }
        #pragma unroll
        for (int mi = 0; mi < 4; mi++)
            #pragma unroll
            for (int ni = 0; ni < 4; ni++)
                acc[mi][ni] = __builtin_amdgcn_mfma_f32_16x16x32_bf16(
                    af[mi], bfr[ni], acc[mi][ni], 0, 0, 0);
    }

    __hip_bfloat16* C = C0 + (long)b * NPIX * DIMLOI;
    #pragma unroll
    for (int ni = 0; ni < 4; ni++) {
        long c = wc * 64 + ni * 16 + r15;
        float bv = bias[c];
        #pragma unroll
        for (int mi = 0; mi < 4; mi++) {
            long rbase = pix0 + wr * 64 + mi * 16 + (lane >> 4) * 4;
            #pragma unroll
            for (int q = 0; q < 4; q++)
                C[(rbase + q) * (long)DIMLOI + c] = __float2bfloat16(acc[mi][ni][q] + bv);
        }
    }
}

// ---------------- MLP bf16 MFMA GEMM (R14-proven loop): 128x128 tile, XCD-chunked ------
// Epilogue (non-SCORE): restage the wave's 64x64 C-subtile through LDS (K-loop buffers
// are dead) -> linear bf16x8 stores, 128B contiguous per row = full 64B HBM sectors
// (fixes the 2x write amplification seen in R15: WRITE 65MB vs 33MB ideal).
#define BM 128
#define BN 128
#define BKK 64

template <bool SCORE>
__global__ __launch_bounds__(256) void gemm_mfma(
    const __hip_bfloat16* __restrict__ A, const __hip_bfloat16* __restrict__ Bt,
    const float* __restrict__ bias, __hip_bfloat16* __restrict__ C,
    int M, int N, int Kd,
    const float* __restrict__ w3, float* __restrict__ slab) {
    int bid = blockIdx.x;
    int xcd = bid & 7, j = bid >> 3;
    int mtpx = (M / BM) >> 3;
    int mt = xcd * mtpx + (j >> 3);
    int nt = j & 7;
    long row0 = (long)mt * BM, col0 = (long)nt * BN;

    __shared__ __align__(16) unsigned short LDSbuf[2 * BM * BKK];   // As | Bs, 32 KB
    unsigned short* As = LDSbuf;
    unsigned short* Bs = LDSbuf + BM * BKK;
    int tid = threadIdx.x;
    int lane = tid & 63, wid = tid >> 6;
    int wr = wid >> 1, wc = wid & 1;

    floatx4 acc[4][4];
    #pragma unroll
    for (int i = 0; i < 4; i++)
        #pragma unroll
        for (int jj = 0; jj < 4; jj++) acc[i][jj] = (floatx4){0.f, 0.f, 0.f, 0.f};

    for (int k0 = 0; k0 < Kd; k0 += BKK) {
        #pragma unroll
        for (int it = 0; it < 4; it++) {
            int slot = wid * 256 + it * 64 + lane;
            int r = slot >> 3, s = slot & 7;
            int ss = s ^ (r & 7);
            gload_lds16(A + (row0 + r) * Kd + k0 + ss * 8,
                        (char*)As + (size_t)(wid * 4096 + it * 1024));
        }
        #pragma unroll
        for (int it = 0; it < 4; it++) {
            int slot = wid * 256 + it * 64 + lane;
            int r = slot >> 3, s = slot & 7;
            int ss = s ^ (r & 7);
            gload_lds16(Bt + (col0 + r) * Kd + k0 + ss * 8,
                        (char*)Bs + (size_t)(wid * 4096 + it * 1024));
        }
        __syncthreads();
        #pragma unroll
        for (int ks = 0; ks < 2; ks++) {
            bf16x8 af[4], bfr[4];
            int s = (lane >> 4) + ks * 4;
            #pragma unroll
            for (int mi = 0; mi < 4; mi++) {
                int R = wr * 64 + mi * 16 + (lane & 15);
                af[mi] = *(const bf16x8*)&As[R * BKK + ((s ^ (R & 7)) << 3)];
            }
            #pragma unroll
            for (int ni = 0; ni < 4; ni++) {
                int Rn = wc * 64 + ni * 16 + (lane & 15);
                bfr[ni] = *(const bf16x8*)&Bs[Rn * BKK + ((s ^ (Rn & 7)) << 3)];
            }
            #pragma unroll
            for (int mi = 0; mi < 4; mi++)
                #pragma unroll
                for (int ni = 0; ni < 4; ni++)
                    acc[mi][ni] = __builtin_amdgcn_mfma_f32_16x16x32_bf16(
                        af[mi], bfr[ni], acc[mi][ni], 0, 0, 0);
        }
        __syncthreads();
    }

    if constexpr (SCORE) {
        int ntile = (int)(col0 / BN);
        #pragma unroll
        for (int mi = 0; mi < 4; mi++) {
            #pragma unroll
            for (int q = 0; q < 4; q++) {
                float p = 0.f;
                #pragma unroll
                for (int ni = 0; ni < 4; ni++) {
                    long c = col0 + wc * 64 + ni * 16 + (lane & 15);
                    float v = fmaxf(acc[mi][ni][q] + bias[c], 0.f);
                    p += v * w3[c];
                }
                #pragma unroll
                for (int off = 1; off < 16; off <<= 1) p += __shfl_xor(p, off);
                if ((lane & 15) == 0) {
                    long row = row0 + wr * 64 + mi * 16 + (lane >> 4) * 4 + q;
                    slab[(long)(ntile * 2 + wc) * MPAD + row] = p;
                }
            }
        }
    } else {
        // restage via LDS (wave-private 4096-elem region), then linear 16B stores
        __hip_bfloat16* stg = (__hip_bfloat16*)LDSbuf + wid * 4096;
        #pragma unroll
        for (int ni = 0; ni < 4; ni++) {
            float bv = bias[col0 + wc * 64 + ni * 16 + (lane & 15)];
            #pragma unroll
            for (int mi = 0; mi < 4; mi++) {
                int rl = mi * 16 + (lane >> 4) * 4;
                #pragma unroll
                for (int q = 0; q < 4; q++) {
                    float v = fmaxf(acc[mi][ni][q] + bv, 0.f);
                    stg[(rl + q) * 64 + ni * 16 + (lane & 15)] = __float2bfloat16(v);
                }
            }
        }
        // each wave reads back only its own region: no barrier needed
        #pragma unroll
        for (int i = 0; i < 8; i++) {
            int rl = i * 8 + (lane >> 3), ch = lane & 7;
            bf16x8 v = *(const bf16x8*)&stg[rl * 64 + ch * 8];
            *(bf16x8*)&C[(row0 + wr * 64 + rl) * (long)N + col0 + wc * 64 + ch * 8] = v;
        }
    }
}

// ---------------- scores: out[r] = b3 + sum_16 slab[i][r] ----------------
__global__ void score_reduce_kernel(const float* __restrict__ slab, const float* __restrict__ b3,
                                    float* __restrict__ out) {
    int r = blockIdx.x * 256 + threadIdx.x;
    if (r >= NROWS) return;
    float s = b3[0];
    #pragma unroll
    for (int i = 0; i < 16; i++) s += slab[(long)i * MPAD + r];
    out[r] = s;
}

// ---------------- LOI bilinear sampling + maxpool-4 + lines/labels emit ----------------
// grid 1024 blocks of 16 rows; XCD g owns rows [2048g, 2048(g+1)) = the h1-gemm M-chunk
// of the same XCD. 16 lanes per row, each owns a 16B d-octet. Phase 1 also writes the
// lines (raw xy endpoints) and zero labels for its rows (replaces lines_kernel).
__global__ __launch_bounds__(256) void loi_sample_kernel(
    const __hip_bfloat16* __restrict__ xf, const float* __restrict__ xy,
    __hip_bfloat16* __restrict__ xp, float* __restrict__ outp) {
    __shared__ int md[16 * 32 * 8];
    int tid = threadIdx.x;
    int bid = blockIdx.x;
    int swz = (bid & 7) * 128 + (bid >> 3);   // 1024 = 8*128, bijective
    int rbase = swz * 16;

    {
        int pt0 = tid * 2;
        int sub = pt0 >> 5;
        int r = rbase + sub;
        int rm = (r < NROWS) ? r : NROWS - 1;
        int b = rm / PPAIR, p = rm % PPAIR;
        int u, v; pair_uv(p, u, v);
        float yu = xy[(b * KTOP + u) * 2 + 0], xu = xy[(b * KTOP + u) * 2 + 1];
        float yv = xy[(b * KTOP + v) * 2 + 0], xv = xy[(b * KTOP + v) * 2 + 1];
        if (((pt0 & 31) == 0) && r < NROWS) {
            float* lines = outp + 2 * NROWS;
            long base = (long)r * 4;
            lines[base + 0] = yu; lines[base + 1] = xu;
            lines[base + 2] = yv; lines[base + 3] = xv;
            outp[NROWS + r] = 0.f;   // labels are identically zero
        }
        #pragma unroll
        for (int pp = 0; pp < 2; pp++) {
            int t = (pt0 + pp) & 31;
            float lam = (float)t * (1.0f / 31.0f);
            float px = yu * lam + yv * (1.f - lam) - 0.5f;
            float py = xu * lam + xv * (1.f - lam) - 0.5f;
            float px0 = fminf(fmaxf(floorf(px), 0.f), 127.f);
            float py0 = fminf(fmaxf(floorf(py), 0.f), 127.f);
            float px1 = fminf(px0 + 1.f, 127.f);
            float py1 = fminf(py0 + 1.f, 127.f);
            int ix0 = (int)px0, iy0 = (int)py0, ix1 = (int)px1, iy1 = (int)py1;
            int base = (pt0 + pp) * 8;
            md[base + 0] = (ix0 * HW + iy0) * (DIMLOI * 2);
            md[base + 1] = (ix1 * HW + iy0) * (DIMLOI * 2);
            md[base + 2] = (ix0 * HW + iy1) * (DIMLOI * 2);
            md[base + 3] = (ix1 * HW + iy1) * (DIMLOI * 2);
            md[base + 4] = __float_as_int((px1 - px) * (py1 - py));
            md[base + 5] = __float_as_int((px - px0) * (py1 - py));
            md[base + 6] = __float_as_int((px1 - px) * (py - py0));
            md[base + 7] = __float_as_int((px - px0) * (py - py0));
        }
    }
    __syncthreads();

    int sub2 = tid >> 4, o = tid & 15;
    int r = rbase + sub2;
    int rm = (r < NROWS) ? r : NROWS - 1;
    int b = rm / PPAIR;
    const char* xfb = (const char*)(xf + (long)b * NPIX * DIMLOI) + o * 16;
    floatx8 mx[8];
    #pragma unroll
    for (int q = 0; q < 8; q++)
        #pragma unroll
        for (int e = 0; e < 8; e++) mx[q][e] = -INFINITY;
    #pragma unroll
    for (int tt = 0; tt < 32; tt++) {
        const int* m = &md[(sub2 * 32 + tt) * 8];
        bf16x8 v00 = *(const bf16x8*)(xfb + m[0]);
        bf16x8 v10 = *(const bf16x8*)(xfb + m[1]);
        bf16x8 v01 = *(const bf16x8*)(xfb + m[2]);
        bf16x8 v11 = *(const bf16x8*)(xfb + m[3]);
        float w00 = __int_as_float(m[4]), w10 = __int_as_float(m[5]);
        float w01 = __int_as_float(m[6]), w11 = __int_as_float(m[7]);
        floatx8 s;
        #pragma unroll
        for (int e = 0; e < 8; e++)
            s[e] = (float)v00[e] * w00 + (float)v10[e] * w10 +
                   (float)v01[e] * w01 + (float)v11[e] * w11;
        mx[tt >> 2] = __builtin_elementwise_max(mx[tt >> 2], s);
    }
    __hip_bfloat16* rowp = xp + (long)r * 1024 + o * 64;
    #pragma unroll
    for (int e = 0; e < 8; e++) {
        bf16x8 outv;
        #pragma unroll
        for (int q = 0; q < 8; q++) outv[q] = (__bf16)mx[q][e];
        *(bf16x8*)(rowp + e * 8) = outv;
    }
}

extern "C" void kernel_launch(void* const* d_in, const int* in_sizes, int n_in,
                              void* d_out, int out_size, void* d_ws, size_t ws_size,
                              hipStream_t stream) {
    const float* inputs   = (const float*)d_in[0];
    const float* features = (const float*)d_in[1];
    const float* fc1_w    = (const float*)d_in[2];
    const float* fc1_b    = (const float*)d_in[3];
    const float* w1       = (const float*)d_in[4];
    const float* b1       = (const float*)d_in[5];
    const float* w2       = (const float*)d_in[6];
    const float* b2       = (const float*)d_in[7];
    const float* w3       = (const float*)d_in[8];
    const float* b3       = (const float*)d_in[9];
    float* out = (float*)d_out;
    float* ws  = (float*)d_ws;

    float* xy   = ws + 65536;                                    // 512 f
    __hip_bfloat16* xfb16 = (__hip_bfloat16*)(ws + 66048);       // 2097152 f
    __hip_bfloat16* xp    = (__hip_bfloat16*)(ws + 4260352);     // 8388608 f (MPAD x 1024 bf16)
    __hip_bfloat16* h1    = (__hip_bfloat16*)(ws + 12648960);    // 8388608 f
    float* slab           = ws + 21037568;                       // 262144 f (16 * MPAD)
    __hip_bfloat16* w1t   = (__hip_bfloat16*)(ws + 21299712);    // 524288 f
    __hip_bfloat16* w2t   = (__hip_bfloat16*)(ws + 21824000);    // 524288 f
    __hip_bfloat16* fc1wb = (__hip_bfloat16*)(ws + 22348288);    // 16384 f
    unsigned long long* tkeys = (unsigned long long*)(ws + 22364672); // 4096 u64

    // weight conversions (one fused kernel)
    prep_weights<<<dim3(32, 32, 3), 256, 0, stream>>>(w1, w2, fc1_w, w1t, w2t, fc1wb);

    // top-128: parallel per-strip NMS+sort, then merge
    nms_sort_kernel<<<dim3(16, NB), 256, 0, stream>>>(inputs, tkeys);
    topk_merge_kernel<<<NB, 512, 0, stream>>>(tkeys, inputs, xy);

    // fused transpose + xf GEMM: reads features directly, writes xf bf16
    xf_fused_kernel<<<dim3(NPIX / 128, 1, NB), 256, 0, stream>>>(
        features, fc1wb, fc1_b, xfb16);

    // loi sampling (also emits lines + zero labels)
    loi_sample_kernel<<<MPAD / 16, 256, 0, stream>>>(xfb16, xy, xp, out);

    // h1 = relu(xp @ w1[:1024] + b1); 128x128 gemm, XCD-chunked, sector-aligned writes
    gemm_mfma<false><<<(MPAD / BM) * 8, 256, 0, stream>>>(
        xp, w1t, b1, h1, MPAD, 1024, 1024, nullptr, nullptr);
    // fused: h2 = relu(h1 @ w2 + b2); slab partials of h2 . w3
    gemm_mfma<true><<<(MPAD / BM) * 8, 256, 0, stream>>>(
        h1, w2t, b2, nullptr, MPAD, 1024, 1024, w3, slab);
    // scores = b3 + sum of 16 slab partials
    score_reduce_kernel<<<(NROWS + 255) / 256, 256, 0, stream>>>(slab, b3, out);
}

// Round 17
// 161.948 us; speedup vs baseline: 1.0362x; 1.0362x over previous
//
#include <hip/hip_runtime.h>
#include <hip/hip_bf16.h>
#include <math.h>

#define HW 128
#define NPIX 16384           // 128*128
#define KTOP 128
#define PPAIR 8128           // 128*127/2
#define NB 2
#define DIMLOI 128
#define NROWS (NB*PPAIR)     // 16256
#define MPAD 16384           // NROWS padded to full tiles (pad rows clamp-duplicated)

typedef __bf16 bf16x8 __attribute__((ext_vector_type(8)));
typedef float floatx4 __attribute__((ext_vector_type(4)));
typedef float floatx8 __attribute__((ext_vector_type(8)));

__device__ __forceinline__ unsigned long long mk_key(float v, int idx) {
    return ((unsigned long long)__float_as_uint(v) << 32) |
           (unsigned long long)(0xFFFFFFFFu - (unsigned)idx);
}

__device__ __forceinline__ unsigned long long shfl_xor_u64(unsigned long long x, int m) {
    unsigned lo = (unsigned)x, hi = (unsigned)(x >> 32);
    lo = __shfl_xor(lo, m);
    hi = __shfl_xor(hi, m);
    return ((unsigned long long)hi << 32) | lo;
}

// bitonic exchange over 256 elems in V[4]; j,k MUST be compile-time (rule #20)
__device__ __forceinline__ void bitonic_stage(unsigned long long V[4], int lane, int j, int k) {
    if (j >= 64) {
        int qm = j >> 6;
        #pragma unroll
        for (int q = 0; q < 4; q++) {
            int p = q ^ qm;
            if (p > q) {
                int i = q * 64 + lane;
                bool desc = ((i & k) == 0);
                unsigned long long a = V[q], b = V[p];
                unsigned long long hi = a > b ? a : b, lo = a > b ? b : a;
                V[q] = desc ? hi : lo;
                V[p] = desc ? lo : hi;
            }
        }
    } else {
        #pragma unroll
        for (int q = 0; q < 4; q++) {
            int i = q * 64 + lane;
            unsigned long long p = shfl_xor_u64(V[q], j);
            bool lower = (lane & j) == 0;
            bool desc = ((i & k) == 0);
            bool keepmax = (desc == lower);
            unsigned long long mx = V[q] > p ? V[q] : p;
            unsigned long long mn = V[q] > p ? p : V[q];
            V[q] = keepmax ? mx : mn;
        }
    }
}

__device__ __forceinline__ void sort256_desc(unsigned long long V[4], int lane) {
    #pragma unroll
    for (int k = 2; k <= 256; k <<= 1)
        #pragma unroll
        for (int j = k >> 1; j >= 1; j >>= 1)
            bitonic_stage(V, lane, j, k);
}

__device__ __forceinline__ void merge256_desc(unsigned long long V[4], int lane) {
    #pragma unroll
    for (int j = 128; j >= 1; j >>= 1)
        bitonic_stage(V, lane, j, 256);
}

__device__ __forceinline__ void gload_lds16(const void* g, void* l) {
    __builtin_amdgcn_global_load_lds(
        (const __attribute__((address_space(1))) void*)g,
        (__attribute__((address_space(3))) void*)l, 16, 0, 0);
}

// pair index p -> (u,v) of triu_indices(128, k=1)
__device__ __forceinline__ void pair_uv(int p, int& u, int& v) {
    int uu = (int)((255.0 - sqrt(65025.0 - 8.0 * (double)p)) * 0.5);
    if (uu < 0) uu = 0;
    while (uu * (255 - uu) / 2 > p) uu--;
    while ((uu + 1) * (255 - (uu + 1)) / 2 <= p) uu++;
    u = uu;
    v = uu + 1 + (p - uu * (255 - uu) / 2);
}

// =========================================================================
// mega_pre: one launch fusing three INDEPENDENT front-end stages
//   blocks [0,32)        : per-strip softmax+NMS+sort (tkeys)
//   blocks [32,544)      : fused transpose + xf GEMM (B self-converted from fp32)
//   blocks [544,2592)    : w1/w2 fp32 [K][N] -> bf16 [N][K] transposes
// All 256 threads; shared memory is a union carved from one block.
// =========================================================================
#define SA 264   // xf A_lds row stride in bf16 (pad breaks 512B stride)
#define SMEM_BYTES (128 * SA * 2 + 128 * 256 * 2)   // 67584 + 65536 = 133120

__global__ __launch_bounds__(256) void mega_pre(
    const float* __restrict__ inputs, const float* __restrict__ features,
    const float* __restrict__ fc1_w, const float* __restrict__ fc1_b,
    const float* __restrict__ w1, const float* __restrict__ w2,
    __hip_bfloat16* __restrict__ w1t, __hip_bfloat16* __restrict__ w2t,
    unsigned long long* __restrict__ tkeys, __hip_bfloat16* __restrict__ xfb16) {
    __shared__ __align__(16) char smem[SMEM_BYTES];
    int bid = blockIdx.x;
    int tid = threadIdx.x;

    if (bid < 32) {
        // ---------------- NMS + per-strip sort ----------------
        float* jm = (float*)smem;                                  // 10*128 floats
        unsigned long long* cand = (unsigned long long*)(smem + 5120);  // 256 u64
        int* scnt = (int*)(smem + 7168);
        int blk = bid & 15, b = bid >> 4;
        int lane = tid & 63;
        int r0  = blk * 8;
        int rlo = (r0 > 0) ? r0 - 1 : 0;
        int rhi = (r0 + 8 < HW) ? r0 + 8 : HW - 1;
        int nrows = rhi - rlo + 1;

        for (int i = tid; i < nrows * HW; i += 256) {
            int pix = rlo * HW + i;
            float l0 = inputs[((long)b * 5 + 0) * NPIX + pix];
            float l1 = inputs[((long)b * 5 + 1) * NPIX + pix];
            float m = fmaxf(l0, l1);
            float e0 = expf(l0 - m), e1 = expf(l1 - m);
            jm[i] = e1 / (e0 + e1);
        }
        cand[tid] = 0ull;
        if (tid == 0) *scnt = 0;
        __syncthreads();

        #pragma unroll
        for (int i = 0; i < 4; i++) {
            int pl = i * 256 + tid;
            int r = r0 + (pl >> 7), c = pl & 127;
            float v = jm[(r - rlo) * HW + c];
            float m = v;
            for (int dr = -1; dr <= 1; dr++) {
                int rr = r + dr;
                if (rr < 0 || rr >= HW) continue;
                for (int dc = -1; dc <= 1; dc++) {
                    int cc = c + dc;
                    if (cc < 0 || cc >= HW) continue;
                    m = fmaxf(m, jm[(rr - rlo) * HW + cc]);
                }
            }
            float nv = (v == m) ? v : 0.f;
            bool has = (nv > 0.f);
            unsigned long long mask = __ballot(has);
            int n = __popcll(mask);
            int wbase = 0;
            if (lane == 0 && n) wbase = atomicAdd(scnt, n);
            wbase = __shfl(wbase, 0);
            if (has) {
                int pos = wbase + __popcll(mask & ((1ull << lane) - 1ull));
                if (pos < 256) cand[pos] = mk_key(nv, r * HW + c);
            }
        }
        __syncthreads();
        if (blk == 0 && tid < 128 && tid >= *scnt) cand[tid] = mk_key(0.f, tid);
        __syncthreads();

        if (tid < 64) {
            unsigned long long V[4];
            #pragma unroll
            for (int q = 0; q < 4; q++) V[q] = cand[q * 64 + lane];
            sort256_desc(V, lane);
            #pragma unroll
            for (int q = 0; q < 2; q++)
                tkeys[((long)b * 16 + blk) * 128 + q * 64 + lane] = V[q];
        }
    } else if (bid < 544) {
        // ---------------- fused transpose + xf GEMM ----------------
        __bf16* A_lds = (__bf16*)smem;                              // 128*SA
        unsigned short* B_lds = (unsigned short*)(smem + 128 * SA * 2);  // 128*256
        int i2 = bid - 32;
        int b = i2 >> 8;            // 0/1
        long pix0 = (long)(i2 & 255) * 64;   // 256 pix-tiles of 64? NO -- keep 128-tiles
        // decode: 512 blocks = 2 batches x 256?? xf uses 128-pix tiles: 128 tiles/batch
        // -> re-decode: tile = i2 & 127, b = i2 >> 7  (i2 in [0,256))
        // blocks [288,544) are duplicates guard:
        if (i2 >= 256) return;
        b = i2 >> 7;
        pix0 = (long)(i2 & 127) * 128;

        int lane = tid & 63, wid = tid >> 6;
        int wr = wid >> 1, wc = wid & 1;

        // stage B from fp32 fc1_w, converting to bf16 into the swizzled layout:
        // target index = r*256 + ((c>>3)^(r&7))*8 + (c&7);  r = tid>>1, c-half = tid&1
        {
            int r = tid >> 1, ch = tid & 1;
            const float* src = fc1_w + (size_t)r * 256 + ch * 128;
            unsigned short* dstrow = B_lds + (size_t)r * 256;
            int r7 = r & 7;
            #pragma unroll
            for (int q4 = 0; q4 < 32; q4++) {
                floatx4 v = *(const floatx4*)(src + q4 * 4);
                int c = ch * 128 + q4 * 4;
                int addr = (((c >> 3) ^ r7) << 3) + (c & 7);
                __hip_bfloat162* d0 = (__hip_bfloat162*)&dstrow[addr];
                d0[0] = __hip_bfloat162{__float2bfloat16(v[0]), __float2bfloat16(v[1])};
                d0[1] = __hip_bfloat162{__float2bfloat16(v[2]), __float2bfloat16(v[3])};
            }
        }
        // stage A: thread owns channel c = tid; float4 along pix, transposed bf16 writes
        {
            int c = tid;
            const float* src = features + ((long)b * 256 + c) * NPIX + pix0;
            #pragma unroll
            for (int p4 = 0; p4 < 32; p4++) {
                floatx4 v = *(const floatx4*)(src + p4 * 4);
                #pragma unroll
                for (int e = 0; e < 4; e++)
                    A_lds[(p4 * 4 + e) * SA + c] = (__bf16)v[e];
            }
        }
        __syncthreads();

        floatx4 acc[4][4];
        #pragma unroll
        for (int i = 0; i < 4; i++)
            #pragma unroll
            for (int j = 0; j < 4; j++) acc[i][j] = (floatx4){0.f, 0.f, 0.f, 0.f};

        int r15 = lane & 15;
        #pragma unroll
        for (int ks = 0; ks < 8; ks++) {
            int s = (lane >> 4) + ks * 4;
            bf16x8 af[4], bfr[4];
            #pragma unroll
            for (int mi = 0; mi < 4; mi++) {
                int R = wr * 64 + mi * 16 + r15;
                af[mi] = *(const bf16x8*)&A_lds[R * SA + s * 8];
            }
            #pragma unroll
            for (int ni = 0; ni < 4; ni++) {
                int Rn = wc * 64 + ni * 16 + r15;
                bfr[ni] = *(const bf16x8*)&B_lds[(size_t)Rn * 256 + ((s ^ (Rn & 7)) << 3)];
            }
            #pragma unroll
            for (int mi = 0; mi < 4; mi++)
                #pragma unroll
                for (int ni = 0; ni < 4; ni++)
                    acc[mi][ni] = __builtin_amdgcn_mfma_f32_16x16x32_bf16(
                        af[mi], bfr[ni], acc[mi][ni], 0, 0, 0);
        }

        __hip_bfloat16* C = xfb16 + (long)b * NPIX * DIMLOI;
        #pragma unroll
        for (int ni = 0; ni < 4; ni++) {
            long c = wc * 64 + ni * 16 + r15;
            float bv = fc1_b[c];
            #pragma unroll
            for (int mi = 0; mi < 4; mi++) {
                long rbase = pix0 + wr * 64 + mi * 16 + (lane >> 4) * 4;
                #pragma unroll
                for (int q = 0; q < 4; q++)
                    C[(rbase + q) * (long)DIMLOI + c] = __float2bfloat16(acc[mi][ni][q] + bv);
            }
        }
    } else {
        // ---------------- w1/w2 transpose to bf16 [N][K] ----------------
        float (*t)[33] = (float(*)[33])smem;
        int i3 = bid - 544;          // 0..2047
        int z = i3 >> 10;
        int rem = i3 & 1023;
        const float* W = z ? w2 : w1;
        __hip_bfloat16* Wt = z ? w2t : w1t;
        int k0 = (rem >> 5) * 32, n0 = (rem & 31) * 32;
        int tx = tid & 31, ty = tid >> 5;
        #pragma unroll
        for (int i = 0; i < 32; i += 8)
            t[ty + i][tx] = W[(long)(k0 + ty + i) * 1024 + n0 + tx];
        __syncthreads();
        #pragma unroll
        for (int i = 0; i < 32; i += 8)
            Wt[(long)(n0 + ty + i) * 1024 + k0 + tx] = __float2bfloat16(t[tx][ty + i]);
    }
}

// ---------------- stage 2: merge 16 sorted lists -> global top-128, emit xy ----------------
__global__ __launch_bounds__(512) void topk_merge_kernel(const unsigned long long* __restrict__ tkeys,
                                                         const float* __restrict__ inp,
                                                         float* __restrict__ xy) {
    __shared__ unsigned long long Lb[16 * 128];
    __shared__ unsigned long long Mb[8 * 128];
    int b = blockIdx.x;
    int tid = threadIdx.x, w = tid >> 6, lane = tid & 63;
    for (int i = tid; i < 16 * 128; i += 512) Lb[i] = tkeys[(long)b * 2048 + i];
    __syncthreads();

    unsigned long long* src = Lb;
    unsigned long long* dst = Mb;
    for (int nact = 8; nact >= 1; nact >>= 1) {
        unsigned long long V[4];
        if (w < nact) {
            #pragma unroll
            for (int q = 0; q < 2; q++) V[q] = src[(2 * w) * 128 + q * 64 + lane];
            #pragma unroll
            for (int q = 2; q < 4; q++) {
                int t = (q - 2) * 64 + lane;
                V[q] = src[(2 * w + 1) * 128 + 127 - t];
            }
            merge256_desc(V, lane);
        }
        __syncthreads();
        if (w < nact) {
            #pragma unroll
            for (int q = 0; q < 2; q++) dst[w * 128 + q * 64 + lane] = V[q];
        }
        __syncthreads();
        unsigned long long* tmp = src; src = dst; dst = tmp;
    }

    if (tid < KTOP) {
        unsigned long long key = src[tid];
        int wi = (int)(0xFFFFFFFFu - (unsigned)(key & 0xFFFFFFFFull));
        int row = wi >> 7, col = wi & 127;
        float l3 = inp[((long)b * 5 + 3) * NPIX + wi];
        float l4 = inp[((long)b * 5 + 4) * NPIX + wi];
        float joy = 1.f / (1.f + expf(-l3)) - 0.5f;
        float jox = 1.f / (1.f + expf(-l4)) - 0.5f;
        xy[(b * KTOP + tid) * 2 + 0] = (float)row + joy + 0.5f;
        xy[(b * KTOP + tid) * 2 + 1] = (float)col + jox + 0.5f;
    }
}

// ---------------- MLP bf16 MFMA GEMM: 128x128 tile, XCD-chunked ----------
#define BM 128
#define BN 128
#define BKK 64

template <bool SCORE>
__global__ __launch_bounds__(256) void gemm_mfma(
    const __hip_bfloat16* __restrict__ A, const __hip_bfloat16* __restrict__ Bt,
    const float* __restrict__ bias, __hip_bfloat16* __restrict__ C,
    int M, int N, int Kd,
    const float* __restrict__ w3, float* __restrict__ slab) {
    int bid = blockIdx.x;
    int xcd = bid & 7, j = bid >> 3;
    int mtpx = (M / BM) >> 3;
    int mt = xcd * mtpx + (j >> 3);
    int nt = j & 7;
    long row0 = (long)mt * BM, col0 = (long)nt * BN;

    __shared__ __align__(16) unsigned short LDSbuf[2 * BM * BKK];   // As | Bs, 32 KB
    unsigned short* As = LDSbuf;
    unsigned short* Bs = LDSbuf + BM * BKK;
    int tid = threadIdx.x;
    int lane = tid & 63, wid = tid >> 6;
    int wr = wid >> 1, wc = wid & 1;

    floatx4 acc[4][4];
    #pragma unroll
    for (int i = 0; i < 4; i++)
        #pragma unroll
        for (int jj = 0; jj < 4; jj++) acc[i][jj] = (floatx4){0.f, 0.f, 0.f, 0.f};

    for (int k0 = 0; k0 < Kd; k0 += BKK) {
        #pragma unroll
        for (int it = 0; it < 4; it++) {
            int slot = wid * 256 + it * 64 + lane;
            int r = slot >> 3, s = slot & 7;
            int ss = s ^ (r & 7);
            gload_lds16(A + (row0 + r) * Kd + k0 + ss * 8,
                        (char*)As + (size_t)(wid * 4096 + it * 1024));
        }
        #pragma unroll
        for (int it = 0; it < 4; it++) {
            int slot = wid * 256 + it * 64 + lane;
            int r = slot >> 3, s = slot & 7;
            int ss = s ^ (r & 7);
            gload_lds16(Bt + (col0 + r) * Kd + k0 + ss * 8,
                        (char*)Bs + (size_t)(wid * 4096 + it * 1024));
        }
        __syncthreads();
        #pragma unroll
        for (int ks = 0; ks < 2; ks++) {
            bf16x8 af[4], bfr[4];
            int s = (lane >> 4) + ks * 4;
            #pragma unroll
            for (int mi = 0; mi < 4; mi++) {
                int R = wr * 64 + mi * 16 + (lane & 15);
                af[mi] = *(const bf16x8*)&As[R * BKK + ((s ^ (R & 7)) << 3)];
            }
            #pragma unroll
            for (int ni = 0; ni < 4; ni++) {
                int Rn = wc * 64 + ni * 16 + (lane & 15);
                bfr[ni] = *(const bf16x8*)&Bs[Rn * BKK + ((s ^ (Rn & 7)) << 3)];
            }
            #pragma unroll
            for (int mi = 0; mi < 4; mi++)
                #pragma unroll
                for (int ni = 0; ni < 4; ni++)
                    acc[mi][ni] = __builtin_amdgcn_mfma_f32_16x16x32_bf16(
                        af[mi], bfr[ni], acc[mi][ni], 0, 0, 0);
        }
        __syncthreads();
    }

    if constexpr (SCORE) {
        int ntile = (int)(col0 / BN);
        #pragma unroll
        for (int mi = 0; mi < 4; mi++) {
            #pragma unroll
            for (int q = 0; q < 4; q++) {
                float p = 0.f;
                #pragma unroll
                for (int ni = 0; ni < 4; ni++) {
                    long c = col0 + wc * 64 + ni * 16 + (lane & 15);
                    float v = fmaxf(acc[mi][ni][q] + bias[c], 0.f);
                    p += v * w3[c];
                }
                #pragma unroll
                for (int off = 1; off < 16; off <<= 1) p += __shfl_xor(p, off);
                if ((lane & 15) == 0) {
                    long row = row0 + wr * 64 + mi * 16 + (lane >> 4) * 4 + q;
                    slab[(long)(ntile * 2 + wc) * MPAD + row] = p;
                }
            }
        }
    } else {
        // restage via LDS (wave-private region), then linear 16B stores (full sectors)
        __hip_bfloat16* stg = (__hip_bfloat16*)LDSbuf + wid * 4096;
        #pragma unroll
        for (int ni = 0; ni < 4; ni++) {
            float bv = bias[col0 + wc * 64 + ni * 16 + (lane & 15)];
            #pragma unroll
            for (int mi = 0; mi < 4; mi++) {
                int rl = mi * 16 + (lane >> 4) * 4;
                #pragma unroll
                for (int q = 0; q < 4; q++) {
                    float v = fmaxf(acc[mi][ni][q] + bv, 0.f);
                    stg[(rl + q) * 64 + ni * 16 + (lane & 15)] = __float2bfloat16(v);
                }
            }
        }
        #pragma unroll
        for (int i = 0; i < 8; i++) {
            int rl = i * 8 + (lane >> 3), ch = lane & 7;
            bf16x8 v = *(const bf16x8*)&stg[rl * 64 + ch * 8];
            *(bf16x8*)&C[(row0 + wr * 64 + rl) * (long)N + col0 + wc * 64 + ch * 8] = v;
        }
    }
}

// ---------------- scores: out[r] = b3 + sum_16 slab[i][r] ----------------
__global__ void score_reduce_kernel(const float* __restrict__ slab, const float* __restrict__ b3,
                                    float* __restrict__ out) {
    int r = blockIdx.x * 256 + threadIdx.x;
    if (r >= NROWS) return;
    float s = b3[0];
    #pragma unroll
    for (int i = 0; i < 16; i++) s += slab[(long)i * MPAD + r];
    out[r] = s;
}

// ---------------- LOI bilinear sampling + maxpool-4 + lines/labels emit ----------------
__global__ __launch_bounds__(256) void loi_sample_kernel(
    const __hip_bfloat16* __restrict__ xf, const float* __restrict__ xy,
    __hip_bfloat16* __restrict__ xp, float* __restrict__ outp) {
    __shared__ int md[16 * 32 * 8];
    int tid = threadIdx.x;
    int bid = blockIdx.x;
    int swz = (bid & 7) * 128 + (bid >> 3);   // 1024 = 8*128, bijective
    int rbase = swz * 16;

    {
        int pt0 = tid * 2;
        int sub = pt0 >> 5;
        int r = rbase + sub;
        int rm = (r < NROWS) ? r : NROWS - 1;
        int b = rm / PPAIR, p = rm % PPAIR;
        int u, v; pair_uv(p, u, v);
        float yu = xy[(b * KTOP + u) * 2 + 0], xu = xy[(b * KTOP + u) * 2 + 1];
        float yv = xy[(b * KTOP + v) * 2 + 0], xv = xy[(b * KTOP + v) * 2 + 1];
        if (((pt0 & 31) == 0) && r < NROWS) {
            float* lines = outp + 2 * NROWS;
            long base = (long)r * 4;
            lines[base + 0] = yu; lines[base + 1] = xu;
            lines[base + 2] = yv; lines[base + 3] = xv;
            outp[NROWS + r] = 0.f;   // labels are identically zero
        }
        #pragma unroll
        for (int pp = 0; pp < 2; pp++) {
            int t = (pt0 + pp) & 31;
            float lam = (float)t * (1.0f / 31.0f);
            float px = yu * lam + yv * (1.f - lam) - 0.5f;
            float py = xu * lam + xv * (1.f - lam) - 0.5f;
            float px0 = fminf(fmaxf(floorf(px), 0.f), 127.f);
            float py0 = fminf(fmaxf(floorf(py), 0.f), 127.f);
            float px1 = fminf(px0 + 1.f, 127.f);
            float py1 = fminf(py0 + 1.f, 127.f);
            int ix0 = (int)px0, iy0 = (int)py0, ix1 = (int)px1, iy1 = (int)py1;
            int base = (pt0 + pp) * 8;
            md[base + 0] = (ix0 * HW + iy0) * (DIMLOI * 2);
            md[base + 1] = (ix1 * HW + iy0) * (DIMLOI * 2);
            md[base + 2] = (ix0 * HW + iy1) * (DIMLOI * 2);
            md[base + 3] = (ix1 * HW + iy1) * (DIMLOI * 2);
            md[base + 4] = __float_as_int((px1 - px) * (py1 - py));
            md[base + 5] = __float_as_int((px - px0) * (py1 - py));
            md[base + 6] = __float_as_int((px1 - px) * (py - py0));
            md[base + 7] = __float_as_int((px - px0) * (py - py0));
        }
    }
    __syncthreads();

    int sub2 = tid >> 4, o = tid & 15;
    int r = rbase + sub2;
    int rm = (r < NROWS) ? r : NROWS - 1;
    int b = rm / PPAIR;
    const char* xfb = (const char*)(xf + (long)b * NPIX * DIMLOI) + o * 16;
    floatx8 mx[8];
    #pragma unroll
    for (int q = 0; q < 8; q++)
        #pragma unroll
        for (int e = 0; e < 8; e++) mx[q][e] = -INFINITY;
    #pragma unroll
    for (int tt = 0; tt < 32; tt++) {
        const int* m = &md[(sub2 * 32 + tt) * 8];
        bf16x8 v00 = *(const bf16x8*)(xfb + m[0]);
        bf16x8 v10 = *(const bf16x8*)(xfb + m[1]);
        bf16x8 v01 = *(const bf16x8*)(xfb + m[2]);
        bf16x8 v11 = *(const bf16x8*)(xfb + m[3]);
        float w00 = __int_as_float(m[4]), w10 = __int_as_float(m[5]);
        float w01 = __int_as_float(m[6]), w11 = __int_as_float(m[7]);
        floatx8 s;
        #pragma unroll
        for (int e = 0; e < 8; e++)
            s[e] = (float)v00[e] * w00 + (float)v10[e] * w10 +
                   (float)v01[e] * w01 + (float)v11[e] * w11;
        mx[tt >> 2] = __builtin_elementwise_max(mx[tt >> 2], s);
    }
    __hip_bfloat16* rowp = xp + (long)r * 1024 + o * 64;
    #pragma unroll
    for (int e = 0; e < 8; e++) {
        bf16x8 outv;
        #pragma unroll
        for (int q = 0; q < 8; q++) outv[q] = (__bf16)mx[q][e];
        *(bf16x8*)(rowp + e * 8) = outv;
    }
}

extern "C" void kernel_launch(void* const* d_in, const int* in_sizes, int n_in,
                              void* d_out, int out_size, void* d_ws, size_t ws_size,
                              hipStream_t stream) {
    const float* inputs   = (const float*)d_in[0];
    const float* features = (const float*)d_in[1];
    const float* fc1_w    = (const float*)d_in[2];
    const float* fc1_b    = (const float*)d_in[3];
    const float* w1       = (const float*)d_in[4];
    const float* b1       = (const float*)d_in[5];
    const float* w2       = (const float*)d_in[6];
    const float* b2       = (const float*)d_in[7];
    const float* w3       = (const float*)d_in[8];
    const float* b3       = (const float*)d_in[9];
    float* out = (float*)d_out;
    float* ws  = (float*)d_ws;

    float* xy   = ws + 65536;                                    // 512 f
    __hip_bfloat16* xfb16 = (__hip_bfloat16*)(ws + 66048);       // 2097152 f
    __hip_bfloat16* xp    = (__hip_bfloat16*)(ws + 4260352);     // 8388608 f (MPAD x 1024 bf16)
    __hip_bfloat16* h1    = (__hip_bfloat16*)(ws + 12648960);    // 8388608 f
    float* slab           = ws + 21037568;                       // 262144 f (16 * MPAD)
    __hip_bfloat16* w1t   = (__hip_bfloat16*)(ws + 21299712);    // 524288 f
    __hip_bfloat16* w2t   = (__hip_bfloat16*)(ws + 21824000);    // 524288 f
    unsigned long long* tkeys = (unsigned long long*)(ws + 22348288); // 4096 u64

    // fused front-end: NMS+sort (32 blk), xf GEMM (256+pad blk), w1/w2 transpose (2048 blk)
    mega_pre<<<2592, 256, 0, stream>>>(inputs, features, fc1_w, fc1_b, w1, w2,
                                       w1t, w2t, tkeys, xfb16);

    topk_merge_kernel<<<NB, 512, 0, stream>>>(tkeys, inputs, xy);

    // loi sampling (also emits lines + zero labels)
    loi_sample_kernel<<<MPAD / 16, 256, 0, stream>>>(xfb16, xy, xp, out);

    // h1 = relu(xp @ w1[:1024] + b1); 128x128 gemm, XCD-chunked, sector-aligned writes
    gemm_mfma<false><<<(MPAD / BM) * 8, 256, 0, stream>>>(
        xp, w1t, b1, h1, MPAD, 1024, 1024, nullptr, nullptr);
    // fused: h2 = relu(h1 @ w2 + b2); slab partials of h2 . w3
    gemm_mfma<true><<<(MPAD / BM) * 8, 256, 0, stream>>>(
        h1, w2t, b2, nullptr, MPAD, 1024, 1024, w3, slab);
    // scores = b3 + sum of 16 slab partials
    score_reduce_kernel<<<(NROWS + 255) / 256, 256, 0, stream>>>(slab, b3, out);
}